// Round 4
// baseline (304.086 us; speedup 1.0000x reference)
//
#include <hip/hip_runtime.h>
#include <stdint.h>

// ---------------- problem constants ----------------
constexpr int B_  = 8, HM = 64, WM = 64, A_ = 42, CIN = 256, HIDN = 512;
constexpr int M_  = HM * WM * A_;          // 172032 anchors per image
constexpr int NA  = B_ * M_;               // 1376256 total anchors
constexpr int HALF = NA / 2;               // 688128 (threefry pairing)
constexpr int KK  = CIN * 9;               // 2304 (im2col K)
constexpr float NEG_T = 0.3f, POS_T = 0.5f;

// positives / per-GT max can only occur in this window (anchors are in PIXEL
// units, GT in feature units <=63.75: overlap forces y<=8, x<=7; margin to 10)
constexpr int WINY = 10, WINX = 10, WPIX = WINY * WINX;
constexpr int PERIMG = A_ * WPIX;                         // 4200

constexpr int MAXPOS = 4096, MAXSEL = 4096, MAXCAND = 16384, MAXPIX = 1024, MAXTIE = 256;
constexpr uint32_t VCAND = 16384u;   // candidate cut on 23-bit uniform; E[cand]=2688 >> P

// ---------------- workspace layout (bytes) ----------------
constexpr size_t OFF_CTRL  = 0;                       // u32[64]; f32 accums at [16..18]
constexpr size_t OFF_BINS  = 256;                     // u32[128]
constexpr size_t OFF_SLOT  = 1024;                    // i32[32768]: 0=unassigned else slot+1
constexpr size_t ZERO_END  = 1024 + 131072;           // memset [0, 132096)
constexpr size_t OFF_PLIST = 132096;                  // i32[MAXPIX]
constexpr size_t OFF_POSL  = 136192;                  // u32[MAXPOS] packed (i | arg<<21)
constexpr size_t OFF_SELL  = 152576;                  // i32[MAXSEL]
constexpr size_t OFF_CAND  = 168960;                  // uint2[MAXCAND]
constexpr size_t OFF_HID   = 300032;                  // f32[MAXPIX*HIDN] post bias+relu
constexpr size_t OFF_PART  = 2397184;                 // f32[4][MAXPIX][HIDN]
constexpr size_t OFF_APATCH= 10785792;                // f32[MAXPIX*KK]
// end = 20222976 (~19.3 MB)

// ctrl: 0 nPos, 1 nSel, 2 nPix, 3 nCand, 10 k6 done-counter; f32 accums ctrl[16..18]

// ---------------- helpers ----------------
__device__ __forceinline__ float iou_pair(float ay0, float ax0, float ay1, float ax1,
                                          float areaA, float g0, float g1, float g2, float g3,
                                          float areaG) {
#pragma clang fp contract(off)
  float ty = fmaxf(ay0, g0), tx = fmaxf(ax0, g1);
  float by = fminf(ay1, g2), bx = fminf(ax1, g3);
  float hy = by - ty; hy = fmaxf(hy, 0.f);
  float hx = bx - tx; hx = fmaxf(hx, 0.f);
  float inter = hy * hx;
  return inter / (areaA + areaG - inter);
}

__device__ __forceinline__ void anchor_box(const float* basef, int a, int y, int x,
                                           float& ay0, float& ax0, float& ay1, float& ax1,
                                           float& areaA) {
#pragma clang fp contract(off)
  double sy = 16.0 * (double)y, sx = 16.0 * (double)x;
  ay0 = (float)((double)basef[a * 4 + 0] + sy);
  ax0 = (float)((double)basef[a * 4 + 1] + sx);
  ay1 = (float)((double)basef[a * 4 + 2] + sy);
  ax1 = (float)((double)basef[a * 4 + 3] + sx);
  areaA = (ay1 - ay0) * (ax1 - ax0);
}

__device__ __forceinline__ void fill_base(float* sbase) {
  int t = threadIdx.x;
  if (t < 42) {
    const double SC[6] = {2.0, 2.5, 3.0, 3.5, 4.0, 5.0};
    const double RA[7] = {0.5, 1.5, 2.0, 2.5, 3.0, 3.5, 4.0};
    int si = t / 7, ri = t - si * 7;
    double h = 16.0 * SC[si] * sqrt(RA[ri]);
    double w = 16.0 * SC[si] * sqrt(1.0 / RA[ri]);
    sbase[t * 4 + 0] = (float)(8.0 - h / 2.0);
    sbase[t * 4 + 1] = (float)(8.0 - w / 2.0);
    sbase[t * 4 + 2] = (float)(8.0 + h / 2.0);
    sbase[t * 4 + 3] = (float)(8.0 + w / 2.0);
  }
}

__device__ __forceinline__ void fill_gt(const float* gt, int b, float* sg, float* sarea,
                                        unsigned* sval) {
  int t = threadIdx.x;
  if (t < 20) {
#pragma clang fp contract(off)
    float g4[4];
    for (int d = 0; d < 4; d++) {
      float v = gt[(b * 20 + t) * 4 + d];
      g4[d] = (v == -1.0f) ? -1.0f : v * 0.0625f;
    }
    unsigned valid = (g4[0] >= 0.0f) ? 1u : 0u;
    if (!valid) { g4[0] = 0.f; g4[1] = 0.f; g4[2] = 1.f; g4[3] = 1.f; }
    sg[t * 4 + 0] = g4[0]; sg[t * 4 + 1] = g4[1]; sg[t * 4 + 2] = g4[2]; sg[t * 4 + 3] = g4[3];
    sarea[t] = (g4[2] - g4[0]) * (g4[3] - g4[1]);
    sval[t] = valid;
  }
}

// claim pixel-image pixg: assign a compact slot exactly once
__device__ __forceinline__ void claim_pixel(char* ws, int pixg) {
  int* slotmap = (int*)(ws + OFF_SLOT);
  if (atomicCAS((unsigned*)&slotmap[pixg], 0u, 0xFFFFFFFFu) == 0u) {
    unsigned s = atomicAdd((unsigned*)(ws + OFF_CTRL) + 2, 1u);
    if (s < MAXPIX) { ((int*)(ws + OFF_PLIST))[s] = pixg; slotmap[pixg] = (int)s + 1; }
    else slotmap[pixg] = -1;
  }
}

__device__ __forceinline__ float softplusf(float x) {
  return fmaxf(x, 0.f) + log1pf(expf(-fabsf(x)));
}
__device__ __forceinline__ float sl1(float d) {
  float ad = fabsf(d);
  return ad < 1.f ? 0.5f * ad * ad : ad - 0.5f;
}

__device__ __forceinline__ void tf_round(uint32_t& x0, uint32_t& x1, int r) {
  x0 += x1; x1 = (x1 << r) | (x1 >> (32 - r)); x1 ^= x0;
}
__device__ __forceinline__ void threefry(uint32_t c0, uint32_t c1, uint32_t& o0, uint32_t& o1) {
  const uint32_t k0 = 0u, k1 = 7u;
  const uint32_t k2 = k0 ^ k1 ^ 0x1BD11BDAu;
  uint32_t x0 = c0 + k0, x1 = c1 + k1;
  tf_round(x0, x1, 13); tf_round(x0, x1, 15); tf_round(x0, x1, 26); tf_round(x0, x1, 6);
  x0 += k1; x1 += k2 + 1u;
  tf_round(x0, x1, 17); tf_round(x0, x1, 29); tf_round(x0, x1, 16); tf_round(x0, x1, 24);
  x0 += k2; x1 += k0 + 2u;
  tf_round(x0, x1, 13); tf_round(x0, x1, 15); tf_round(x0, x1, 26); tf_round(x0, x1, 6);
  x0 += k0; x1 += k1 + 3u;
  tf_round(x0, x1, 17); tf_round(x0, x1, 29); tf_round(x0, x1, 16); tf_round(x0, x1, 24);
  x0 += k1; x1 += k2 + 4u;
  tf_round(x0, x1, 13); tf_round(x0, x1, 15); tf_round(x0, x1, 26); tf_round(x0, x1, 6);
  x0 += k2; x1 += k0 + 5u;
  o0 = x0; o1 = x1;
}

// ---------------- KA: threefry -> candidates + 128-bin histogram ----------------
__global__ void __launch_bounds__(256) kA(char* ws) {
  int p = blockIdx.x * 256 + threadIdx.x;   // [0, HALF)
  uint32_t o0, o1; threefry((uint32_t)p, (uint32_t)(p + HALF), o0, o1);
  uint32_t v0 = o0 >> 9, v1 = o1 >> 9;
  unsigned* ctrl = (unsigned*)(ws + OFF_CTRL);
  unsigned* bins = (unsigned*)(ws + OFF_BINS);
  uint2* cand = (uint2*)(ws + OFF_CAND);
  if (v0 < VCAND) {
    unsigned s = atomicAdd(&ctrl[3], 1u);
    if (s < MAXCAND) cand[s] = make_uint2(v0, (unsigned)p);
    atomicAdd(&bins[v0 >> 7], 1u);
  }
  if (v1 < VCAND) {
    unsigned s = atomicAdd(&ctrl[3], 1u);
    if (s < MAXCAND) cand[s] = make_uint2(v1, (unsigned)(p + HALF));
    atomicAdd(&bins[v1 >> 7], 1u);
  }
}

// ---------------- KPos: fused per-GT max + positive assignment (1 block/image) ----------------
__global__ void __launch_bounds__(512) kPos(const float* __restrict__ gt, char* ws) {
  __shared__ float sbase[168], sg[80], sarea[20];
  __shared__ unsigned sval[20];
  __shared__ int smax[20];
  int b = blockIdx.x, t = threadIdx.x;
  fill_base(sbase);
  fill_gt(gt, b, sg, sarea, sval);
  if (t < 20) smax[t] = 0;
  __syncthreads();
  // pass 1: per-GT max IoU over the window
  for (int idx = t; idx < PERIMG; idx += 512) {
    int a = idx / WPIX, pp = idx - a * WPIX;
    int y = pp / WINX, x = pp - y * WINX;
    float ay0, ax0, ay1, ax1, areaA;
    anchor_box(sbase, a, y, x, ay0, ax0, ay1, ax1, areaA);
    for (int n = 0; n < 20; n++) {
      if (!sval[n]) continue;
      float io = iou_pair(ay0, ax0, ay1, ax1, areaA,
                          sg[n * 4], sg[n * 4 + 1], sg[n * 4 + 2], sg[n * 4 + 3], sarea[n]);
      if (io > 0.f) atomicMax(&smax[n], __float_as_int(io));
    }
  }
  __syncthreads();
  // pass 2: positive test (exact per-GT-argmax ties; io>POS_T impossible but kept)
  unsigned* ctrl = (unsigned*)(ws + OFF_CTRL);
  for (int idx = t; idx < PERIMG; idx += 512) {
    int a = idx / WPIX, pp = idx - a * WPIX;
    int y = pp / WINX, x = pp - y * WINX;
    float ay0, ax0, ay1, ax1, areaA;
    anchor_box(sbase, a, y, x, ay0, ax0, ay1, ax1, areaA);
    float best = -1.f; int arg = 0; bool pos = false;
    for (int n = 0; n < 20; n++) {
      float io = 0.f;
      if (sval[n]) io = iou_pair(ay0, ax0, ay1, ax1, areaA,
                                 sg[n * 4], sg[n * 4 + 1], sg[n * 4 + 2], sg[n * 4 + 3], sarea[n]);
      if (io > best) { best = io; arg = n; }
      float mg = __int_as_float(smax[n]);
      pos = pos || ((io == mg) && (mg > 0.f)) || (io > POS_T);
    }
    if (pos) {
      int pix = y * 64 + x;
      int i = b * M_ + pix * 42 + a;
      unsigned slot = atomicAdd(&ctrl[0], 1u);
      if (slot < MAXPOS) ((unsigned*)(ws + OFF_POSL))[slot] = (unsigned)i | ((unsigned)arg << 21);
      claim_pixel(ws, b * 4096 + pix);
    }
  }
}

// ---------------- KSel: exact P-smallest selection over candidate list ----------------
__global__ void __launch_bounds__(256) kSel(char* ws) {
  __shared__ unsigned bins[128];
  __shared__ uint2 ties[MAXTIE];
  __shared__ unsigned tcnt, s_r, s_ucut;
  __shared__ int s_icut, s_cutbin;
  unsigned* ctrl = (unsigned*)(ws + OFF_CTRL);
  const uint2* cand = (const uint2*)(ws + OFF_CAND);
  int t = threadIdx.x;
  unsigned P = min(ctrl[0], (unsigned)MAXPOS);
  unsigned nc = min(ctrl[3], (unsigned)MAXCAND);
  if (t < 128) bins[t] = ((const unsigned*)(ws + OFF_BINS))[t];
  if (t == 0) tcnt = 0;
  __syncthreads();
  if (t == 0) {
    unsigned cum = 0; int c = 0;
    for (; c < 128; c++) { if (cum + bins[c] >= P) break; cum += bins[c]; }
    if (c == 128) c = 127;
    s_cutbin = c; s_r = (P > cum) ? (P - cum) : 0u;
  }
  __syncthreads();
  int cutbin = s_cutbin;
  for (unsigned j = t; j < nc; j += 256)
    if ((int)(cand[j].x >> 7) == cutbin) {
      unsigned k = atomicAdd(&tcnt, 1u);
      if (k < MAXTIE) ties[k] = cand[j];
    }
  __syncthreads();
  if (t == 0) {
    unsigned n = min(tcnt, (unsigned)MAXTIE);
    unsigned r = s_r; if (r > n) r = n;
    unsigned curV = 0; int curI = -1;
    for (unsigned s = 0; s < r; s++) {
      unsigned bu = 0xFFFFFFFFu; int bi = 0x7FFFFFFF;
      for (unsigned j = 0; j < n; j++) {
        unsigned u = ties[j].x; int idx = (int)ties[j].y;
        bool gtcur = (u > curV) || (u == curV && idx > curI);
        bool ltbest = (u < bu) || (u == bu && idx < bi);
        if (gtcur && ltbest) { bu = u; bi = idx; }
      }
      curV = bu; curI = bi;
    }
    if (r == 0) { curV = 0; curI = -1; }
    s_ucut = curV; s_icut = curI;
  }
  __syncthreads();
  unsigned ucut = s_ucut; int icut = s_icut;
  for (unsigned j = t; j < nc; j += 256) {
    unsigned v = cand[j].x; int i = (int)cand[j].y;
    if (v < ucut || (v == ucut && i <= icut)) {
      unsigned slot = atomicAdd(&ctrl[1], 1u);
      if (slot < MAXSEL) {
        ((int*)(ws + OFF_SELL))[slot] = i;
        int b = i / M_; int m = i - b * M_;
        claim_pixel(ws, b * 4096 + m / 42);
      }
    }
  }
}

// ---------------- K4c: im2col for needed pixels ----------------
__global__ void __launch_bounds__(256) k4c_im2col(const float* __restrict__ fm, char* ws) {
  unsigned* ctrl = (unsigned*)(ws + OFF_CTRL);
  int npix = min((int)ctrl[2], MAXPIX);
  int blk = blockIdx.x;
  if (blk >= npix) return;
  int pixg = ((const int*)(ws + OFF_PLIST))[blk];
  int b = pixg >> 12, pix = pixg & 4095;
  int y = pix >> 6, x = pix & 63;
  float* Ap = (float*)(ws + OFF_APATCH) + (size_t)blk * KK;
  for (int idx = threadIdx.x; idx < KK; idx += 256) {
    int ic = idx / 9, r = idx - ic * 9;
    int dy = r / 3, dx = r - dy * 3;
    int yy = y + dy - 1, xx = x + dx - 1;
    float v = 0.f;
    if (yy >= 0 && yy < 64 && xx >= 0 && xx < 64)
      v = fm[(((size_t)b * CIN + ic) * 64 + yy) * 64 + xx];
    Ap[idx] = v;
  }
}

// ---------------- K5: sparse conv1 tiled GEMM, partial-sum stores (no atomics) ----------------
// tile 64px x 64oc, K-split 4 (KCH=576), kstep 16, double-buffered LDS.
constexpr int KSPL = 4, KCH = KK / KSPL;     // 576
constexpr int NST = KCH / 16;                // 36 stages

__global__ void __launch_bounds__(256) k5_gemm(const float* __restrict__ w1, char* ws) {
  unsigned* ctrl = (unsigned*)(ws + OFF_CTRL);
  int npix = min((int)ctrl[2], MAXPIX);
  int bid = blockIdx.x;
  int strip = bid & 15, r2 = bid >> 4;
  int och = r2 & 7, ks = r2 >> 3;
  int px0 = strip * 64;
  if (px0 >= npix) return;
  int oc0 = och * 64, kb = ks * KCH;
  __shared__ float As[2][16][64];
  __shared__ float Wsm[2][16][64];
  const float* Ap = (const float*)(ws + OFF_APATCH);
  int t = threadIdx.x;
  int ls = t & 63, kc = t >> 6;         // staging: 64 cols x 4 k-rows (float4 each)
  int tx = t & 15, ty = t >> 4;         // compute: px=px0+tx*4.., oc=oc0+ty*4..
  bool pxok = (px0 + ls) < npix;
  const float* Ag = Ap + (size_t)(px0 + ls) * KK + kb + kc * 4;
  const float* Wg = w1 + (size_t)(oc0 + ls) * KK + kb + kc * 4;
  float4 av = pxok ? *(const float4*)Ag : float4{0.f, 0.f, 0.f, 0.f};
  float4 wv = *(const float4*)Wg;
  As[0][kc * 4 + 0][ls] = av.x; As[0][kc * 4 + 1][ls] = av.y;
  As[0][kc * 4 + 2][ls] = av.z; As[0][kc * 4 + 3][ls] = av.w;
  Wsm[0][kc * 4 + 0][ls] = wv.x; Wsm[0][kc * 4 + 1][ls] = wv.y;
  Wsm[0][kc * 4 + 2][ls] = wv.z; Wsm[0][kc * 4 + 3][ls] = wv.w;
  float acc[4][4] = {};
  __syncthreads();
  for (int s = 0; s < NST; s++) {
    int cur = s & 1;
    float4 an = {0.f, 0.f, 0.f, 0.f}, wn = {0.f, 0.f, 0.f, 0.f};
    bool more = (s + 1 < NST);
    if (more) {
      if (pxok) an = *(const float4*)(Ag + (s + 1) * 16);
      wn = *(const float4*)(Wg + (s + 1) * 16);
    }
#pragma unroll
    for (int k = 0; k < 16; k++) {
      float4 a4 = *(const float4*)&As[cur][k][tx * 4];
      float4 w4 = *(const float4*)&Wsm[cur][k][ty * 4];
      acc[0][0] += w4.x * a4.x; acc[0][1] += w4.x * a4.y;
      acc[0][2] += w4.x * a4.z; acc[0][3] += w4.x * a4.w;
      acc[1][0] += w4.y * a4.x; acc[1][1] += w4.y * a4.y;
      acc[1][2] += w4.y * a4.z; acc[1][3] += w4.y * a4.w;
      acc[2][0] += w4.z * a4.x; acc[2][1] += w4.z * a4.y;
      acc[2][2] += w4.z * a4.z; acc[2][3] += w4.z * a4.w;
      acc[3][0] += w4.w * a4.x; acc[3][1] += w4.w * a4.y;
      acc[3][2] += w4.w * a4.z; acc[3][3] += w4.w * a4.w;
    }
    if (more) {
      int nxt = cur ^ 1;
      As[nxt][kc * 4 + 0][ls] = an.x; As[nxt][kc * 4 + 1][ls] = an.y;
      As[nxt][kc * 4 + 2][ls] = an.z; As[nxt][kc * 4 + 3][ls] = an.w;
      Wsm[nxt][kc * 4 + 0][ls] = wn.x; Wsm[nxt][kc * 4 + 1][ls] = wn.y;
      Wsm[nxt][kc * 4 + 2][ls] = wn.z; Wsm[nxt][kc * 4 + 3][ls] = wn.w;
    }
    __syncthreads();
  }
  float* part = (float*)(ws + OFF_PART) + (size_t)ks * MAXPIX * HIDN;
#pragma unroll
  for (int j = 0; j < 4; j++) {
    int px = px0 + tx * 4 + j;
    if (px < npix) {
      float4 v = {acc[0][j], acc[1][j], acc[2][j], acc[3][j]};
      *(float4*)&part[(size_t)px * HIDN + oc0 + ty * 4] = v;
    }
  }
}

// ---------------- K5r: reduce K-split partials + bias + relu ----------------
__global__ void __launch_bounds__(256) k5r_reduce(const float* __restrict__ b1, char* ws) {
  unsigned* ctrl = (unsigned*)(ws + OFF_CTRL);
  int npix = min((int)ctrl[2], MAXPIX);
  int id = blockIdx.x * 256 + threadIdx.x;
  int px = id >> 9, oc = id & 511;
  if (px >= npix) return;
  const float* part = (const float*)(ws + OFF_PART);
  size_t o = (size_t)px * HIDN + oc;
  float s = part[o];
  s += part[o + (size_t)1 * MAXPIX * HIDN];
  s += part[o + (size_t)2 * MAXPIX * HIDN];
  s += part[o + (size_t)3 * MAXPIX * HIDN];
  s += b1[oc];
  ((float*)(ws + OFF_HID))[o] = s > 0.f ? s : 0.f;
}

// ---------------- K6: heads + loss + finalize ----------------
__global__ void __launch_bounds__(256) k6_head(const float* __restrict__ gt,
                                               const float* __restrict__ cw,
                                               const float* __restrict__ cb,
                                               const float* __restrict__ rw,
                                               const float* __restrict__ rb,
                                               char* ws, float* out) {
  __shared__ float sbase[168], sg[640];
  int t = threadIdx.x;
  fill_base(sbase);
  if (t < 160) {
#pragma clang fp contract(off)
    float g4[4];
    for (int d = 0; d < 4; d++) {
      float v = gt[t * 4 + d];
      g4[d] = (v == -1.0f) ? -1.0f : v * 0.0625f;
    }
    if (!(g4[0] >= 0.0f)) { g4[0] = 0.f; g4[1] = 0.f; g4[2] = 1.f; g4[3] = 1.f; }
    sg[t * 4 + 0] = g4[0]; sg[t * 4 + 1] = g4[1]; sg[t * 4 + 2] = g4[2]; sg[t * 4 + 3] = g4[3];
  }
  __syncthreads();
  unsigned* ctrl = (unsigned*)(ws + OFF_CTRL);
  float* accum = (float*)(ctrl + 16);
  int np = min((int)ctrl[0], MAXPOS);
  int ns = min((int)ctrl[1], MAXSEL);
  int nent = np + ns;
  const unsigned* posl = (const unsigned*)(ws + OFF_POSL);
  const int* sell = (const int*)(ws + OFF_SELL);
  const int* slotmap = (const int*)(ws + OFF_SLOT);
  const float* hid = (const float*)(ws + OFF_HID);
  int lane = t & 63;
  int gwave = blockIdx.x * 4 + (t >> 6);
  int nwaves = gridDim.x * 4;
  for (int e = gwave; e < nent; e += nwaves) {
    bool isPos = e < np;
    int i, arg = 0;
    if (isPos) { unsigned pck = posl[e]; i = (int)(pck & 0x1FFFFFu); arg = (int)(pck >> 21); }
    else i = sell[e - np];
    int b = i / M_; int m = i - b * M_;
    int pix = m / 42; int a = m - pix * 42;
    int y = pix >> 6, x = pix & 63;
    int slot = slotmap[b * 4096 + pix] - 1;
    if (slot < 0 || slot >= MAXPIX) continue;
    float h[8];
    const float* hr = hid + (size_t)slot * HIDN;
#pragma unroll
    for (int j = 0; j < 8; j++) h[j] = hr[lane + j * 64];
    const float* cwr = cw + (size_t)a * HIDN;
    float cp = 0.f;
#pragma unroll
    for (int j = 0; j < 8; j++) cp += h[j] * cwr[lane + j * 64];
#pragma unroll
    for (int off = 32; off >= 1; off >>= 1) cp += __shfl_xor(cp, off, 64);
    float conf = cp + cb[a];
    if (isPos) {
      float rp[4];
#pragma unroll
      for (int d = 0; d < 4; d++) {
        const float* rwr = rw + (size_t)(a * 4 + d) * HIDN;
        float sd = 0.f;
#pragma unroll
        for (int j = 0; j < 8; j++) sd += h[j] * rwr[lane + j * 64];
#pragma unroll
        for (int off = 32; off >= 1; off >>= 1) sd += __shfl_xor(sd, off, 64);
        rp[d] = sd + rb[a * 4 + d];
      }
      if (lane == 0) {
#pragma clang fp contract(off)
        float ay0, ax0, ay1, ax1, areaA;
        anchor_box(sbase, a, y, x, ay0, ax0, ay1, ax1, areaA);
        const float* g = sg + (size_t)(b * 20 + arg) * 4;
        float acy = (ay0 + ay1) * 0.5f, acx = (ax0 + ax1) * 0.5f;
        float ah = ay1 - ay0, aw = ax1 - ax0;
        float gcy = (g[0] + g[2]) * 0.5f, gcx = (g[1] + g[3]) * 0.5f;
        float gh = g[2] - g[0], gw = g[3] - g[1];
        float t0 = (gcy - acy) / ah, t1 = (gcx - acx) / aw;
        float t2 = logf(gh / ah), t3 = logf(gw / aw);
        float sL = sl1(rp[0] - t0) + sl1(rp[1] - t1) + sl1(rp[2] - t2) + sl1(rp[3] - t3);
        atomicAdd(&accum[2], sL);
        atomicAdd(&accum[0], softplusf(-conf));
      }
    } else {
      if (lane == 0) atomicAdd(&accum[1], softplusf(conf));
    }
  }
  __syncthreads();
  if (t == 0) {
    __threadfence();
    unsigned done = atomicAdd(&ctrl[10], 1u);
    if (done == gridDim.x - 1) {
      __threadfence();
      float P = (float)min((int)ctrl[0], MAXPOS);
      float S = (float)min((int)ctrl[1], MAXSEL);
      float cls = 0.5f * (accum[0] / P + accum[1] / S);
      out[0] = cls + accum[2] / (P * 4.0f);
    }
  }
}

// ---------------- launcher ----------------
extern "C" void kernel_launch(void* const* d_in, const int* in_sizes, int n_in,
                              void* d_out, int out_size, void* d_ws, size_t ws_size,
                              hipStream_t stream) {
  const float* fm = (const float*)d_in[0];
  const float* gt = (const float*)d_in[1];
  const float* w1 = (const float*)d_in[3];
  const float* b1 = (const float*)d_in[4];
  const float* cw = (const float*)d_in[5];
  const float* cb = (const float*)d_in[6];
  const float* rw = (const float*)d_in[7];
  const float* rb = (const float*)d_in[8];
  char* ws = (char*)d_ws;
  float* out = (float*)d_out;

  hipMemsetAsync(ws, 0, ZERO_END, stream);

  kA<<<HALF / 256, 256, 0, stream>>>(ws);
  kPos<<<B_, 512, 0, stream>>>(gt, ws);
  kSel<<<1, 256, 0, stream>>>(ws);
  k4c_im2col<<<MAXPIX, 256, 0, stream>>>(fm, ws);
  k5_gemm<<<16 * 8 * KSPL, 256, 0, stream>>>(w1, ws);
  k5r_reduce<<<(MAXPIX * HIDN) / 256, 256, 0, stream>>>(b1, ws);
  k6_head<<<128, 256, 0, stream>>>(gt, cw, cb, rw, rb, ws, out);
}